// Round 4
// baseline (1645.918 us; speedup 1.0000x reference)
//
#include <hip/hip_runtime.h>
#include <hip/hip_bf16.h>

typedef __attribute__((ext_vector_type(8))) short short8;
typedef __attribute__((ext_vector_type(4))) float float4v;

#if __has_builtin(__builtin_amdgcn_sdot4)
#define DOT4(a, b, c) __builtin_amdgcn_sdot4((int)(a), (int)(b), (c), false)
#else
__device__ __forceinline__ int dot4_(int a, int b, int c) {
  c += (int)(signed char)(a) * (int)(signed char)(b);
  c += (int)(signed char)(a >> 8) * (int)(signed char)(b >> 8);
  c += (int)(signed char)(a >> 16) * (int)(signed char)(b >> 16);
  c += (a >> 24) * (b >> 24);
  return c;
}
#define DOT4(a, b, c) dot4_((int)(a), (int)(b), (c))
#endif

__device__ __forceinline__ float sigmoidf_(float x) {
  return __fdividef(1.f, 1.f + __expf(-x));
}
__device__ __forceinline__ float tanhf_(float x) {
  float e = __expf(2.f * x);
  return 1.f - __fdividef(2.f, e + 1.f);
}
__device__ __forceinline__ float bflo(unsigned int v) {
  return __uint_as_float(v << 16);
}
__device__ __forceinline__ float bfhi(unsigned int v) {
  return __uint_as_float(v & 0xffff0000u);
}

// quad (4-lane) butterflies via DPP quad_perm (VALU, not DS pipe)
template <int CTRL>
__device__ __forceinline__ int qadd_i(int v) {
  return v + __builtin_amdgcn_update_dpp(0, v, CTRL, 0xF, 0xF, true);
}
template <int CTRL>
__device__ __forceinline__ float qmax_f(float v) {
  int r = __builtin_amdgcn_update_dpp(0, __float_as_int(v), CTRL, 0xF, 0xF, true);
  return fmaxf(v, __int_as_float(r));
}
#define XOR1 0xB1  // quad_perm [1,0,3,2]
#define XOR2 0x4E  // quad_perm [2,3,0,1]

// ---------------------------------------------------------------------------
// Kernel A: projected embedding tables.
// Logical col n in [0,2048): dir=n>>10, r=n&1023, gate=r>>8, u=r&255.
// Stored at out[m*2048 + dir*1024 + u*4 + gate]  ([row][dir][unit][i,f,g,o]).
// ---------------------------------------------------------------------------
__global__ __launch_bounds__(256) void proj_gemm(
    const float* __restrict__ A, int rowsA, int Kdim, int col_off,
    const float* __restrict__ wf, const float* __restrict__ wb,
    const float* __restrict__ bf1, const float* __restrict__ bf2,
    const float* __restrict__ bb1, const float* __restrict__ bb2,
    __hip_bfloat16* __restrict__ out, int add_bias) {
  __shared__ __align__(16) __hip_bfloat16 As[64][40];
  __shared__ __align__(16) __hip_bfloat16 Bs[256][40];
  const int tid = threadIdx.x;
  const int m0 = blockIdx.x * 64, n0 = blockIdx.y * 256;
  const int lane = tid & 63, wave = tid >> 6;
  const int quad = lane >> 4, lm = lane & 15;
  float4v acc[16] = {};
  const int ksteps = (Kdim + 31) >> 5;
  const int r = tid >> 2, c0 = (tid & 3) << 3;
  for (int ks = 0; ks < ksteps; ++ks) {
    const int k0 = ks << 5;
#pragma unroll
    for (int e = 0; e < 8; ++e) {
      int kk = k0 + c0 + e;
      float av = (m0 + r < rowsA && kk < Kdim) ? A[(m0 + r) * Kdim + kk] : 0.f;
      As[r][c0 + e] = __float2bfloat16(av);
    }
    {
      int n = n0 + tid;
      const float* __restrict__ wrow =
          (n < 1024) ? (wf + n * 450 + col_off) : (wb + (n - 1024) * 450 + col_off);
#pragma unroll
      for (int e2 = 0; e2 < 16; ++e2) {
        int kk = k0 + e2 * 2;
        float b0 = 0.f, b1 = 0.f;
        if (kk < Kdim) {  // Kdim even: pairs never straddle
          float2 v = *(const float2*)(wrow + kk);
          b0 = v.x;
          b1 = v.y;
        }
        Bs[tid][e2 * 2] = __float2bfloat16(b0);
        Bs[tid][e2 * 2 + 1] = __float2bfloat16(b1);
      }
    }
    __syncthreads();
    short8 af = *(const short8*)(&As[wave * 16 + lm][quad * 8]);
#pragma unroll
    for (int t = 0; t < 16; ++t) {
      short8 bf = *(const short8*)(&Bs[t * 16 + lm][quad * 8]);
      acc[t] = __builtin_amdgcn_mfma_f32_16x16x32_bf16(af, bf, acc[t], 0, 0, 0);
    }
    __syncthreads();
  }
#pragma unroll
  for (int t = 0; t < 16; ++t) {
#pragma unroll
    for (int rr = 0; rr < 4; ++rr) {
      int m = m0 + wave * 16 + quad * 4 + rr;
      int col = n0 + t * 16 + lm;
      if (m < rowsA) {
        float v = acc[t][rr];
        if (add_bias)
          v += (col < 1024) ? (bf1[col] + bf2[col]) : (bb1[col - 1024] + bb2[col - 1024]);
        int dir = col >> 10, r2 = col & 1023;
        int gate = r2 >> 8, u = r2 & 255;
        out[m * 2048 + dir * 1024 + u * 4 + gate] = __float2bfloat16(v);
      }
    }
  }
}

// ---------------------------------------------------------------------------
// Kernel B: BiLSTM recurrence, int8 dot4, 1024 threads/chain.
// Quad q owns unit q (4 gate rows i,f,g,o); lane e holds K-slice [64e,64e+64).
// W = 4 rows x 16 uints = 64 VGPRs -> total live ~110 < 128 (16-wave block
// at 1 block/CU REQUIRES <=128 VGPR; design fits by construction, no spill).
// Per step: 4 ds_read_b128 (h) + 64 v_dot4 + 8 DPP quad-reduce + e==0 pointwise.
// ---------------------------------------------------------------------------
__global__ __launch_bounds__(1024, 1) void lstm_kernel(
    const float* __restrict__ whh_f, const float* __restrict__ whh_b,
    const int* __restrict__ x, const int* __restrict__ ptags, const int* __restrict__ gtags,
    const char* __restrict__ char_proj, const char* __restrict__ pin_proj,
    const char* __restrict__ tag_proj, __hip_bfloat16* __restrict__ h_out) {
  __shared__ __align__(16) int4 sidx[512];            // byte offsets per t
  __shared__ __align__(16) signed char hbuf[2][256];  // h int8, double-buffered

  const int tid = threadIdx.x;
  const int q = tid >> 2, e = tid & 3;
  const int chain = blockIdx.x;
  const int dir = chain >> 7;
  const int b = chain & 127;
  const float* __restrict__ whh = dir ? whh_b : whh_f;

  // stage index byte-offsets (table row pitch = 2048 bf16 = 4096 B)
  if (tid < 512)
    sidx[tid] = make_int4(x[b * 512 + tid] * 4096, ptags[b * 512 + tid] * 4096,
                          gtags[b * 512 + tid] * 4096, 0);
  if (tid < 16) ((int4*)hbuf[0])[tid] = make_int4(0, 0, 0, 0);

  // ---- int8-quantize weight slice: 4 gate rows of unit q, K in [64e,64e+64) ----
  unsigned int W[4][16];
  float sc[4];
#pragma unroll
  for (int gg = 0; gg < 4; ++gg) {
    const float* __restrict__ wr = whh + (gg * 256 + q) * 256 + e * 64;
    float mx = 0.f;
#pragma unroll
    for (int k4 = 0; k4 < 16; ++k4) {
      float4 v = ((const float4*)wr)[k4];
      mx = fmaxf(mx, fmaxf(fmaxf(fabsf(v.x), fabsf(v.y)), fmaxf(fabsf(v.z), fabsf(v.w))));
    }
    mx = qmax_f<XOR1>(mx);
    mx = qmax_f<XOR2>(mx);  // full-row max across the 4 k-slices
    float inv = (mx > 0.f) ? __fdividef(127.f, mx) : 0.f;
    sc[gg] = (mx > 0.f) ? (mx / (127.f * 127.f)) : 0.f;  // combined w*h dequant scale
#pragma unroll
    for (int k4 = 0; k4 < 16; ++k4) {
      float4 v = ((const float4*)wr)[k4];
      int b0 = (int)rintf(v.x * inv), b1 = (int)rintf(v.y * inv);
      int b2 = (int)rintf(v.z * inv), b3 = (int)rintf(v.w * inv);
      W[gg][k4] = (unsigned int)((b0 & 0xff) | ((b1 & 0xff) << 8) | ((b2 & 0xff) << 16) |
                                 ((b3 & 0xff) << 24));
    }
  }
  __syncthreads();

  const int pre_off = dir * 2048 + q * 8;  // bytes within a table row
  float cst = 0.f;

  // prefetch step 0 pre-gates (e==0 lanes)
  int t_cur = dir ? 511 : 0;
  uint2 pc = {}, pp = {}, pt = {};
  if (e == 0) {
    int4 ix = sidx[t_cur];
    pc = *(const uint2*)(char_proj + ix.x + pre_off);
    pp = *(const uint2*)(pin_proj + ix.y + pre_off);
    pt = *(const uint2*)(tag_proj + ix.z + pre_off);
  }

  for (int s = 0; s < 512; ++s) {
    const int t = t_cur;
    const uint2 cv = pc, pv = pp, gv = pt;
    const int tn = dir ? (t > 0 ? t - 1 : 0) : (t < 511 ? t + 1 : 511);
    t_cur = tn;

    // h slice (64 int8 = 4 x b128), buffer parity = s
    const uint4* hv = (const uint4*)(&hbuf[s & 1][e * 64]);
    uint4 H0 = hv[0], H1 = hv[1], H2 = hv[2], H3 = hv[3];

    // prefetch next step's pre-gates
    if (e == 0) {
      int4 ix = sidx[tn];
      pc = *(const uint2*)(char_proj + ix.x + pre_off);
      pp = *(const uint2*)(pin_proj + ix.y + pre_off);
      pt = *(const uint2*)(tag_proj + ix.z + pre_off);
    }

    int acc[4];
#pragma unroll
    for (int gg = 0; gg < 4; ++gg) {
      int a = 0;
      a = DOT4(W[gg][0], H0.x, a);
      a = DOT4(W[gg][1], H0.y, a);
      a = DOT4(W[gg][2], H0.z, a);
      a = DOT4(W[gg][3], H0.w, a);
      a = DOT4(W[gg][4], H1.x, a);
      a = DOT4(W[gg][5], H1.y, a);
      a = DOT4(W[gg][6], H1.z, a);
      a = DOT4(W[gg][7], H1.w, a);
      a = DOT4(W[gg][8], H2.x, a);
      a = DOT4(W[gg][9], H2.y, a);
      a = DOT4(W[gg][10], H2.z, a);
      a = DOT4(W[gg][11], H2.w, a);
      a = DOT4(W[gg][12], H3.x, a);
      a = DOT4(W[gg][13], H3.y, a);
      a = DOT4(W[gg][14], H3.z, a);
      a = DOT4(W[gg][15], H3.w, a);
      acc[gg] = a;
    }
    // quad butterfly: all 4 lanes get full-K sums
#pragma unroll
    for (int gg = 0; gg < 4; ++gg) {
      int v = qadd_i<XOR1>(acc[gg]);
      acc[gg] = qadd_i<XOR2>(v);
    }

    if (e == 0) {
      // pre-gates: (i,f) in .x, (g,o) in .y of each table's uint2
      float gi = bflo(cv.x) + bflo(pv.x) + bflo(gv.x) + (float)acc[0] * sc[0];
      float gf = bfhi(cv.x) + bfhi(pv.x) + bfhi(gv.x) + (float)acc[1] * sc[1];
      float gg_ = bflo(cv.y) + bflo(pv.y) + bflo(gv.y) + (float)acc[2] * sc[2];
      float go = bfhi(cv.y) + bfhi(pv.y) + bfhi(gv.y) + (float)acc[3] * sc[3];
      cst = sigmoidf_(gf) * cst + sigmoidf_(gi) * tanhf_(gg_);
      float hval = sigmoidf_(go) * tanhf_(cst);
      hbuf[(s + 1) & 1][q] = (signed char)(int)rintf(hval * 127.f);
      h_out[((size_t)chain * 512 + t) * 256 + q] = __float2bfloat16(hval);
    }
    __syncthreads();
  }
}

// ---------------------------------------------------------------------------
// Kernel C: emissions GEMM. em[b*512+t][k] = Hcat[n]·w_out[k] + b_out[k]
// ---------------------------------------------------------------------------
__global__ __launch_bounds__(256) void emis_kernel(
    const __hip_bfloat16* __restrict__ h_glob, const float* __restrict__ w_out,
    const float* __restrict__ b_out, float* __restrict__ em) {
  __shared__ __align__(16) __hip_bfloat16 As[64][40];
  __shared__ __align__(16) __hip_bfloat16 Bs[32][40];
  const int tid = threadIdx.x;
  const int n0 = blockIdx.x * 64;
  const int lane = tid & 63, wave = tid >> 6, quad = lane >> 4, lm = lane & 15;
  float4v acc[2] = {};
  const int r = tid >> 2, c0 = (tid & 3) << 3;
  const int rb = tid >> 3, cb = (tid & 7) << 2;
  for (int ks = 0; ks < 16; ++ks) {
    const int j0 = ks * 32;
    const int dirk = j0 >> 8, jin = j0 & 255;
    const int n = n0 + r, bb = n >> 9, tt = n & 511;
    const uint4* src =
        (const uint4*)(h_glob + ((size_t)(dirk * 128 + bb) * 512 + tt) * 256 + jin + c0);
    *(uint4*)(&As[r][c0]) = *src;
#pragma unroll
    for (int e = 0; e < 4; ++e) {
      float v = (rb < 20) ? w_out[rb * 512 + j0 + cb + e] : 0.f;
      Bs[rb][cb + e] = __float2bfloat16(v);
    }
    __syncthreads();
    short8 af = *(const short8*)(&As[wave * 16 + lm][quad * 8]);
#pragma unroll
    for (int t2 = 0; t2 < 2; ++t2) {
      short8 bf = *(const short8*)(&Bs[t2 * 16 + lm][quad * 8]);
      acc[t2] = __builtin_amdgcn_mfma_f32_16x16x32_bf16(af, bf, acc[t2], 0, 0, 0);
    }
    __syncthreads();
  }
#pragma unroll
  for (int t2 = 0; t2 < 2; ++t2) {
#pragma unroll
    for (int rr = 0; rr < 4; ++rr) {
      int col = t2 * 16 + lm;
      if (col < 20) {
        int n = n0 + wave * 16 + quad * 4 + rr;
        em[(size_t)n * 20 + col] = acc[t2][rr] + b_out[col];
      }
    }
  }
}

// ---------------------------------------------------------------------------
// Kernel D: CRF forward NLL. 1 wave per batch element.
// ---------------------------------------------------------------------------
__global__ __launch_bounds__(64) void crf_kernel(
    const float* __restrict__ em, const int* __restrict__ y,
    const float* __restrict__ start_trans, const float* __restrict__ end_trans,
    const float* __restrict__ trans, float* __restrict__ partials) {
  const int b = blockIdx.x;
  const int lane = threadIdx.x;
  const int jj = lane < 20 ? lane : 19;
  const bool act = lane < 20;
  __shared__ float sea[2][64];
  const float* __restrict__ emb = em + (size_t)b * 512 * 20;
  const int* __restrict__ yb = y + b * 512;

  // ---- gold-path score, parallel over t ----
  float s_part = 0.f;
#pragma unroll
  for (int i = 0; i < 8; ++i) {
    int t = lane + 64 * i;
    int yc = yb[t];
    float v = emb[t * 20 + yc];
    v += (t == 0) ? start_trans[yc] : trans[yb[t - 1] * 20 + yc];
    s_part += v;
  }
#pragma unroll
  for (int k = 32; k >= 1; k >>= 1) s_part += __shfl_xor(s_part, k, 64);
  float score = s_part + end_trans[yb[511]];

  // ---- forward algorithm ----
  float ET[20];
#pragma unroll
  for (int i = 0; i < 20; ++i) ET[i] = __expf(trans[i * 20 + jj]);
  float alpha = act ? (start_trans[jj] + emb[jj]) : -1e30f;
  float P = alpha;
#pragma unroll
  for (int k = 32; k >= 1; k >>= 1) P = fmaxf(P, __shfl_xor(P, k, 64));

  float eC = emb[1 * 20 + jj];
  float eN = emb[2 * 20 + jj];
  for (int t = 1; t < 512; ++t) {
    if ((t & 15) == 0) {
      P = alpha;
#pragma unroll
      for (int k = 32; k >= 1; k >>= 1) P = fmaxf(P, __shfl_xor(P, k, 64));
    }
    sea[t & 1][lane] = __expf(alpha - P);
    int tf = t + 2 < 512 ? t + 2 : 511;
    float eF = emb[tf * 20 + jj];
    __syncthreads();
    float s0 = 0.f, s1 = 0.f;
#pragma unroll
    for (int i = 0; i < 20; i += 2) {
      s0 += sea[t & 1][i] * ET[i];
      s1 += sea[t & 1][i + 1] * ET[i + 1];
    }
    if (act) alpha = P + __logf(s0 + s1) + eC;
    eC = eN;
    eN = eF;
  }
  float v = act ? (alpha + end_trans[jj]) : -1e30f;
  float Pz = v;
#pragma unroll
  for (int k = 32; k >= 1; k >>= 1) Pz = fmaxf(Pz, __shfl_xor(Pz, k, 64));
  float e2 = __expf(v - Pz);
#pragma unroll
  for (int k = 32; k >= 1; k >>= 1) e2 += __shfl_xor(e2, k, 64);
  float logZ = Pz + __logf(e2);
  if (lane == 0) partials[b] = logZ - score;
}

__global__ __launch_bounds__(128) void reduce_kernel(const float* __restrict__ partials,
                                                     float* __restrict__ out) {
  const int tid = threadIdx.x;
  float v = partials[tid];
#pragma unroll
  for (int k = 32; k >= 1; k >>= 1) v += __shfl_xor(v, k, 64);
  __shared__ float tmp[2];
  if ((tid & 63) == 0) tmp[tid >> 6] = v;
  __syncthreads();
  if (tid == 0) out[0] = tmp[0] + tmp[1];
}

// ---------------------------------------------------------------------------
extern "C" void kernel_launch(void* const* d_in, const int* in_sizes, int n_in,
                              void* d_out, int out_size, void* d_ws, size_t ws_size,
                              hipStream_t stream) {
  const int* x = (const int*)d_in[0];
  const int* y = (const int*)d_in[1];
  const int* pre_tags = (const int*)d_in[2];
  const int* pinyin_tags = (const int*)d_in[3];
  const float* char_emb = (const float*)d_in[5];
  const float* tag_emb = (const float*)d_in[6];
  const float* pinyin_emb = (const float*)d_in[7];
  const float* w_ih_f = (const float*)d_in[8];
  const float* w_hh_f = (const float*)d_in[9];
  const float* b_ih_f = (const float*)d_in[10];
  const float* b_hh_f = (const float*)d_in[11];
  const float* w_ih_b = (const float*)d_in[12];
  const float* w_hh_b = (const float*)d_in[13];
  const float* b_ih_b = (const float*)d_in[14];
  const float* b_hh_b = (const float*)d_in[15];
  const float* w_out = (const float*)d_in[16];
  const float* b_out = (const float*)d_in[17];
  const float* start_trans = (const float*)d_in[18];
  const float* end_trans = (const float*)d_in[19];
  const float* trans = (const float*)d_in[20];

  char* ws = (char*)d_ws;
  __hip_bfloat16* char_proj = (__hip_bfloat16*)(ws);            // 10002*2048*2 = 40968192
  __hip_bfloat16* pin_proj = (__hip_bfloat16*)(ws + 40968192);  // 500*2048*2  = 2048000
  __hip_bfloat16* tag_proj = (__hip_bfloat16*)(ws + 43016192);  // 20*2048*2   = 81920
  __hip_bfloat16* h_glob = (__hip_bfloat16*)(ws + 43098112);    // 2*128*512*256*2 = 67108864
  float* em = (float*)(ws + 110206976);                         // 65536*20*4 = 5242880
  float* partials = (float*)(ws + 115449856);                   // 128*4

  proj_gemm<<<dim3(157, 8), 256, 0, stream>>>(char_emb, 10002, 300, 0, w_ih_f, w_ih_b,
                                              nullptr, nullptr, nullptr, nullptr, char_proj, 0);
  proj_gemm<<<dim3(8, 8), 256, 0, stream>>>(pinyin_emb, 500, 100, 300, w_ih_f, w_ih_b,
                                            nullptr, nullptr, nullptr, nullptr, pin_proj, 0);
  proj_gemm<<<dim3(1, 8), 256, 0, stream>>>(tag_emb, 20, 50, 400, w_ih_f, w_ih_b,
                                            b_ih_f, b_hh_f, b_ih_b, b_hh_b, tag_proj, 1);

  lstm_kernel<<<256, 1024, 0, stream>>>(w_hh_f, w_hh_b, x, pinyin_tags, pre_tags,
                                        (const char*)char_proj, (const char*)pin_proj,
                                        (const char*)tag_proj, h_glob);

  emis_kernel<<<1024, 256, 0, stream>>>(h_glob, w_out, b_out, em);
  crf_kernel<<<128, 64, 0, stream>>>(em, y, start_trans, end_trans, trans, partials);
  reduce_kernel<<<1, 128, 0, stream>>>(partials, (float*)d_out);
}